// Round 1
// baseline (368.308 us; speedup 1.0000x reference)
//
#include <hip/hip_runtime.h>
#include <hip/hip_bf16.h>

#define N_NODES_C 50000
#define F_IN_C 64
#define HID_C 128
#define N_GRAPHS_C 500
#define N_CLS_C 10
#define MLP_HID_C 50

__device__ __forceinline__ float bcast_lane(float v, int lane) {
    return __uint_as_float(__builtin_amdgcn_readlane(__float_as_uint(v), lane));
}

// ---------------------------------------------------------------------------
// Stage 1: scatter-add neighbor features. One wave (64 lanes) per edge,
// lane = feature. Coalesced 256B read of x[src] row, 64 contiguous f32
// atomics into agg[dst] row. Lane 0 bumps the degree counter.
// ---------------------------------------------------------------------------
__global__ __launch_bounds__(256) void edge_agg_kernel(
    const float* __restrict__ x,
    const int* __restrict__ src,
    const int* __restrict__ dst,
    float* __restrict__ agg,
    float* __restrict__ deg,
    int n_edges)
{
    int tid = blockIdx.x * blockDim.x + threadIdx.x;
    int e = tid >> 6;
    int f = tid & 63;
    if (e >= n_edges) return;
    int s = src[e];
    int d = dst[e];
    float v = x[(size_t)s * F_IN_C + f];
    atomicAdd(&agg[(size_t)d * F_IN_C + f], v);
    if (f == 0) atomicAdd(&deg[d], 1.0f);
}

// ---------------------------------------------------------------------------
// Stage 2: per-node fused linear: emb = (agg/deg) @ Wn + x @ Ws + b.
// W (combined 128x128 f32 = 64KB) staged in LDS. Each wave owns groups of
// 4 nodes; node rows live in registers, broadcast via v_readlane under a
// fully unrolled k-loop. Also does ReLU + graph-pool atomics.
// ---------------------------------------------------------------------------
__global__ __launch_bounds__(256) void node_emb_kernel(
    const float* __restrict__ x,
    const float* __restrict__ agg,
    const float* __restrict__ deg,
    const float* __restrict__ Wn,
    const float* __restrict__ Ws,
    const float* __restrict__ bias,
    const int* __restrict__ batch,
    float* __restrict__ emb_out,
    float* __restrict__ pooled,
    float* __restrict__ cnt)
{
    __shared__ float sW[128 * 128];   // rows 0..63 = Wn, rows 64..127 = Ws
    int t = threadIdx.x;
    for (int i = t; i < 64 * 128; i += 256) {
        sW[i] = Wn[i];
        sW[64 * 128 + i] = Ws[i];
    }
    __syncthreads();

    int wave = t >> 6;
    int lane = t & 63;
    int gwave = blockIdx.x * 4 + wave;
    int nwaves = gridDim.x * 4;

    float b_lo = bias[lane];
    float b_hi = bias[64 + lane];

    for (int nb = gwave * 4; nb < N_NODES_C; nb += nwaves * 4) {
        // rows for 4 nodes in registers (lane = k index)
        float a0 = agg[(size_t)(nb + 0) * F_IN_C + lane] * (1.0f / fmaxf(deg[nb + 0], 1.0f));
        float a1 = agg[(size_t)(nb + 1) * F_IN_C + lane] * (1.0f / fmaxf(deg[nb + 1], 1.0f));
        float a2 = agg[(size_t)(nb + 2) * F_IN_C + lane] * (1.0f / fmaxf(deg[nb + 2], 1.0f));
        float a3 = agg[(size_t)(nb + 3) * F_IN_C + lane] * (1.0f / fmaxf(deg[nb + 3], 1.0f));
        float x0 = x[(size_t)(nb + 0) * F_IN_C + lane];
        float x1 = x[(size_t)(nb + 1) * F_IN_C + lane];
        float x2 = x[(size_t)(nb + 2) * F_IN_C + lane];
        float x3 = x[(size_t)(nb + 3) * F_IN_C + lane];

        float al0 = b_lo, ah0 = b_hi;
        float al1 = b_lo, ah1 = b_hi;
        float al2 = b_lo, ah2 = b_hi;
        float al3 = b_lo, ah3 = b_hi;

        #pragma unroll
        for (int k = 0; k < 64; ++k) {
            float wlo = sW[k * 128 + lane];
            float whi = sW[k * 128 + 64 + lane];
            float v0 = bcast_lane(a0, k);
            float v1 = bcast_lane(a1, k);
            float v2 = bcast_lane(a2, k);
            float v3 = bcast_lane(a3, k);
            al0 += v0 * wlo; ah0 += v0 * whi;
            al1 += v1 * wlo; ah1 += v1 * whi;
            al2 += v2 * wlo; ah2 += v2 * whi;
            al3 += v3 * wlo; ah3 += v3 * whi;
        }
        #pragma unroll
        for (int k = 0; k < 64; ++k) {
            float wlo = sW[(64 + k) * 128 + lane];
            float whi = sW[(64 + k) * 128 + 64 + lane];
            float v0 = bcast_lane(x0, k);
            float v1 = bcast_lane(x1, k);
            float v2 = bcast_lane(x2, k);
            float v3 = bcast_lane(x3, k);
            al0 += v0 * wlo; ah0 += v0 * whi;
            al1 += v1 * wlo; ah1 += v1 * whi;
            al2 += v2 * wlo; ah2 += v2 * whi;
            al3 += v3 * wlo; ah3 += v3 * whi;
        }

        // write emb (pre-ReLU), then ReLU + pool
        emb_out[(size_t)(nb + 0) * HID_C + lane]      = al0;
        emb_out[(size_t)(nb + 0) * HID_C + 64 + lane] = ah0;
        emb_out[(size_t)(nb + 1) * HID_C + lane]      = al1;
        emb_out[(size_t)(nb + 1) * HID_C + 64 + lane] = ah1;
        emb_out[(size_t)(nb + 2) * HID_C + lane]      = al2;
        emb_out[(size_t)(nb + 2) * HID_C + 64 + lane] = ah2;
        emb_out[(size_t)(nb + 3) * HID_C + lane]      = al3;
        emb_out[(size_t)(nb + 3) * HID_C + 64 + lane] = ah3;

        #pragma unroll
        for (int i = 0; i < 4; ++i) {
            int node = nb + i;
            int g = batch[node];
            float hl, hh;
            if (i == 0) { hl = al0; hh = ah0; }
            else if (i == 1) { hl = al1; hh = ah1; }
            else if (i == 2) { hl = al2; hh = ah2; }
            else { hl = al3; hh = ah3; }
            hl = fmaxf(hl, 0.0f);
            hh = fmaxf(hh, 0.0f);
            atomicAdd(&pooled[(size_t)g * HID_C + lane], hl);
            atomicAdd(&pooled[(size_t)g * HID_C + 64 + lane], hh);
            if (lane == 0) atomicAdd(&cnt[g], 1.0f);
        }
    }
}

// ---------------------------------------------------------------------------
// Stage 3: per-graph MLP head + log_softmax. One block (64 threads) per graph.
// ---------------------------------------------------------------------------
__global__ __launch_bounds__(64) void mlp_head_kernel(
    const float* __restrict__ pooled,
    const float* __restrict__ cnt,
    const float* __restrict__ W1,
    const float* __restrict__ b1,
    const float* __restrict__ W2,
    const float* __restrict__ b2,
    float* __restrict__ logits_out)
{
    int g = blockIdx.x;
    int t = threadIdx.x;
    __shared__ float sp[HID_C];
    __shared__ float sh[MLP_HID_C];
    __shared__ float sl[N_CLS_C];

    float inv = 1.0f / fmaxf(cnt[g], 1.0f);
    sp[t] = pooled[(size_t)g * HID_C + t] * inv;
    sp[t + 64] = pooled[(size_t)g * HID_C + t + 64] * inv;
    __syncthreads();

    if (t < MLP_HID_C) {
        float a = b1[t];
        #pragma unroll 8
        for (int k = 0; k < HID_C; ++k) a += sp[k] * W1[k * MLP_HID_C + t];
        sh[t] = fmaxf(a, 0.0f);
    }
    __syncthreads();

    if (t < N_CLS_C) {
        float a = b2[t];
        #pragma unroll
        for (int k = 0; k < MLP_HID_C; ++k) a += sh[k] * W2[k * N_CLS_C + t];
        sl[t] = a;
    }
    __syncthreads();

    if (t < N_CLS_C) {
        float m = sl[0];
        #pragma unroll
        for (int i = 1; i < N_CLS_C; ++i) m = fmaxf(m, sl[i]);
        float sum = 0.0f;
        #pragma unroll
        for (int i = 0; i < N_CLS_C; ++i) sum += expf(sl[i] - m);
        logits_out[(size_t)g * N_CLS_C + t] = sl[t] - m - logf(sum);
    }
}

extern "C" void kernel_launch(void* const* d_in, const int* in_sizes, int n_in,
                              void* d_out, int out_size, void* d_ws, size_t ws_size,
                              hipStream_t stream) {
    const float* x      = (const float*)d_in[0];
    const int*   ei     = (const int*)d_in[1];
    const int*   batch  = (const int*)d_in[2];
    const float* Wn     = (const float*)d_in[3];
    const float* Ws     = (const float*)d_in[4];
    const float* bias   = (const float*)d_in[5];
    const float* W1     = (const float*)d_in[6];
    const float* b1     = (const float*)d_in[7];
    const float* W2     = (const float*)d_in[8];
    const float* b2     = (const float*)d_in[9];

    float* out = (float*)d_out;

    int n_edges = in_sizes[1] / 2;
    const int* src = ei;
    const int* dst = ei + n_edges;

    // workspace layout (f32): agg[N*64] | deg[N] | pooled[G*128] | cnt[G]
    float* agg    = (float*)d_ws;
    float* deg    = agg + (size_t)N_NODES_C * F_IN_C;
    float* pooled = deg + N_NODES_C;
    float* cnt    = pooled + (size_t)N_GRAPHS_C * HID_C;
    size_t zero_bytes = ((size_t)N_NODES_C * F_IN_C + N_NODES_C +
                         (size_t)N_GRAPHS_C * HID_C + N_GRAPHS_C) * sizeof(float);
    hipMemsetAsync(d_ws, 0, zero_bytes, stream);

    {
        long long total = (long long)n_edges * 64;
        int block = 256;
        long long grid = (total + block - 1) / block;
        edge_agg_kernel<<<(int)grid, block, 0, stream>>>(x, src, dst, agg, deg, n_edges);
    }

    node_emb_kernel<<<512, 256, 0, stream>>>(x, agg, deg, Wn, Ws, bias, batch,
                                             out, pooled, cnt);

    mlp_head_kernel<<<N_GRAPHS_C, 64, 0, stream>>>(pooled, cnt, W1, b1, W2, b2,
                                                   out + (size_t)N_NODES_C * HID_C);
}

// Round 2
// 201.665 us; speedup vs baseline: 1.8263x; 1.8263x over previous
//
#include <hip/hip_runtime.h>
#include <hip/hip_bf16.h>

#define N_NODES_C 50000
#define F_IN_C 64
#define HID_C 128
#define N_GRAPHS_C 500
#define N_CLS_C 10
#define MLP_HID_C 50
#define SCAN_TILE 1024
#define N_SCAN_BLK ((N_NODES_C + SCAN_TILE - 1) / SCAN_TILE)   // 49

__device__ __forceinline__ float bcast_lane_f(float v, int lane) {
    return __uint_as_float(__builtin_amdgcn_readlane(__float_as_uint(v), lane));
}
__device__ __forceinline__ int bcast_lane_i(int v, int lane) {
    return __builtin_amdgcn_readlane(v, lane);
}

// ---------------------------------------------------------------------------
// CSR build stage 1: degree histogram (int atomics, 800K ops)
// ---------------------------------------------------------------------------
__global__ __launch_bounds__(256) void hist_kernel(
    const int* __restrict__ dst, int* __restrict__ deg_i, int n_edges)
{
    int e = blockIdx.x * blockDim.x + threadIdx.x;
    if (e >= n_edges) return;
    atomicAdd(&deg_i[dst[e]], 1);
}

// CSR build stage 2a: per-1024-tile sums
__global__ __launch_bounds__(256) void scan1_kernel(
    const int* __restrict__ deg_i, int* __restrict__ bsums, int n)
{
    __shared__ int s[256];
    int base = blockIdx.x * SCAN_TILE;
    int t = threadIdx.x;
    int sum = 0;
    #pragma unroll
    for (int j = 0; j < 4; ++j) {
        int i = base + t * 4 + j;
        sum += (i < n) ? deg_i[i] : 0;
    }
    s[t] = sum;
    __syncthreads();
    for (int off = 128; off > 0; off >>= 1) {
        if (t < off) s[t] += s[t + off];
        __syncthreads();
    }
    if (t == 0) bsums[blockIdx.x] = s[0];
}

// CSR build stage 2b: serial scan of 49 tile sums (trivial)
__global__ void scan2_kernel(const int* __restrict__ bsums,
                             int* __restrict__ bprefix,
                             int* __restrict__ off, int nb, int n)
{
    if (threadIdx.x == 0 && blockIdx.x == 0) {
        int acc = 0;
        for (int i = 0; i < nb; ++i) { bprefix[i] = acc; acc += bsums[i]; }
        off[n] = acc;
    }
}

// CSR build stage 2c: intra-tile exclusive scan -> offsets
__global__ __launch_bounds__(256) void scan3_kernel(
    const int* __restrict__ deg_i, const int* __restrict__ bprefix,
    int* __restrict__ off, int n)
{
    __shared__ int s[256];
    int base = blockIdx.x * SCAN_TILE;
    int t = threadIdx.x;
    int v[4];
    int sum = 0;
    #pragma unroll
    for (int j = 0; j < 4; ++j) {
        int i = base + t * 4 + j;
        v[j] = (i < n) ? deg_i[i] : 0;
        sum += v[j];
    }
    s[t] = sum;
    __syncthreads();
    for (int o = 1; o < 256; o <<= 1) {
        int tmp = (t >= o) ? s[t - o] : 0;
        __syncthreads();
        s[t] += tmp;
        __syncthreads();
    }
    int run = s[t] - sum + bprefix[blockIdx.x];
    #pragma unroll
    for (int j = 0; j < 4; ++j) {
        int i = base + t * 4 + j;
        if (i < n) off[i] = run;
        run += v[j];
    }
}

// CSR build stage 3: scatter src ids into adjacency (int atomics, 800K ops)
__global__ __launch_bounds__(256) void scatter_kernel(
    const int* __restrict__ src, const int* __restrict__ dst,
    const int* __restrict__ off, int* __restrict__ cursor,
    int* __restrict__ adj, int n_edges)
{
    int e = blockIdx.x * blockDim.x + threadIdx.x;
    if (e >= n_edges) return;
    int d = dst[e];
    int p = atomicAdd(&cursor[d], 1);
    adj[off[d] + p] = src[e];
}

// ---------------------------------------------------------------------------
// Fused gather + linear: per wave, 4 nodes. Gather neighbor rows from x via
// CSR (coalesced 256B row reads, cache-resident), mean, then LDS-staged
// 128x128 matmul: emb = mean_agg @ Wn + x @ Ws + b. Writes pre-ReLU emb.
// ---------------------------------------------------------------------------
__global__ __launch_bounds__(512) void gather_emb_kernel(
    const float* __restrict__ x,
    const int* __restrict__ adj,
    const int* __restrict__ off,
    const int* __restrict__ deg_i,
    const float* __restrict__ Wn,
    const float* __restrict__ Ws,
    const float* __restrict__ bias,
    float* __restrict__ emb_out)
{
    __shared__ float sW[128 * 128];   // rows 0..63 = Wn, rows 64..127 = Ws
    int t = threadIdx.x;
    for (int i = t; i < 64 * 128; i += 512) {
        sW[i] = Wn[i];
        sW[64 * 128 + i] = Ws[i];
    }
    __syncthreads();

    int wave = t >> 6;
    int lane = t & 63;
    int nb = (blockIdx.x * 8 + wave) * 4;
    if (nb >= N_NODES_C) return;

    // --- gather 4 nodes' neighbor means into registers (lane = feature) ---
    float a[4];
    #pragma unroll
    for (int i = 0; i < 4; ++i) {
        int node = nb + i;
        int o = off[node];
        int d = deg_i[node];
        float acc = 0.0f;
        for (int j0 = 0; j0 < d; j0 += 64) {
            int c = d - j0; if (c > 64) c = 64;
            int nid = (lane < c) ? adj[o + j0 + lane] : 0;
            int j = 0;
            for (; j + 4 <= c; j += 4) {
                int s0 = bcast_lane_i(nid, j + 0);
                int s1 = bcast_lane_i(nid, j + 1);
                int s2 = bcast_lane_i(nid, j + 2);
                int s3 = bcast_lane_i(nid, j + 3);
                float v0 = x[(size_t)s0 * F_IN_C + lane];
                float v1 = x[(size_t)s1 * F_IN_C + lane];
                float v2 = x[(size_t)s2 * F_IN_C + lane];
                float v3 = x[(size_t)s3 * F_IN_C + lane];
                acc += v0; acc += v1; acc += v2; acc += v3;
            }
            for (; j < c; ++j) {
                int s0 = bcast_lane_i(nid, j);
                acc += x[(size_t)s0 * F_IN_C + lane];
            }
        }
        a[i] = acc * (1.0f / fmaxf((float)d, 1.0f));
    }

    float x0 = x[(size_t)(nb + 0) * F_IN_C + lane];
    float x1 = x[(size_t)(nb + 1) * F_IN_C + lane];
    float x2 = x[(size_t)(nb + 2) * F_IN_C + lane];
    float x3 = x[(size_t)(nb + 3) * F_IN_C + lane];

    float b_lo = bias[lane];
    float b_hi = bias[64 + lane];
    float al0 = b_lo, ah0 = b_hi, al1 = b_lo, ah1 = b_hi;
    float al2 = b_lo, ah2 = b_hi, al3 = b_lo, ah3 = b_hi;

    #pragma unroll
    for (int k = 0; k < 64; ++k) {
        float wlo = sW[k * 128 + lane];
        float whi = sW[k * 128 + 64 + lane];
        float v0 = bcast_lane_f(a[0], k);
        float v1 = bcast_lane_f(a[1], k);
        float v2 = bcast_lane_f(a[2], k);
        float v3 = bcast_lane_f(a[3], k);
        al0 += v0 * wlo; ah0 += v0 * whi;
        al1 += v1 * wlo; ah1 += v1 * whi;
        al2 += v2 * wlo; ah2 += v2 * whi;
        al3 += v3 * wlo; ah3 += v3 * whi;
    }
    #pragma unroll
    for (int k = 0; k < 64; ++k) {
        float wlo = sW[(64 + k) * 128 + lane];
        float whi = sW[(64 + k) * 128 + 64 + lane];
        float v0 = bcast_lane_f(x0, k);
        float v1 = bcast_lane_f(x1, k);
        float v2 = bcast_lane_f(x2, k);
        float v3 = bcast_lane_f(x3, k);
        al0 += v0 * wlo; ah0 += v0 * whi;
        al1 += v1 * wlo; ah1 += v1 * whi;
        al2 += v2 * wlo; ah2 += v2 * whi;
        al3 += v3 * wlo; ah3 += v3 * whi;
    }

    emb_out[(size_t)(nb + 0) * HID_C + lane]      = al0;
    emb_out[(size_t)(nb + 0) * HID_C + 64 + lane] = ah0;
    emb_out[(size_t)(nb + 1) * HID_C + lane]      = al1;
    emb_out[(size_t)(nb + 1) * HID_C + 64 + lane] = ah1;
    emb_out[(size_t)(nb + 2) * HID_C + lane]      = al2;
    emb_out[(size_t)(nb + 2) * HID_C + 64 + lane] = ah2;
    emb_out[(size_t)(nb + 3) * HID_C + lane]      = al3;
    emb_out[(size_t)(nb + 3) * HID_C + 64 + lane] = ah3;
}

// ---------------------------------------------------------------------------
// Graph boundaries: batch is sorted, find start[g] for g in [0, N_GRAPHS].
// ---------------------------------------------------------------------------
__global__ __launch_bounds__(256) void bounds_kernel(
    const int* __restrict__ batch, int* __restrict__ start, int n)
{
    int i = blockIdx.x * blockDim.x + threadIdx.x;
    if (i >= n) return;
    int b = batch[i];
    if (i == 0) {
        for (int g = 0; g <= b; ++g) start[g] = 0;
    } else {
        int p = batch[i - 1];
        for (int g = p + 1; g <= b; ++g) start[g] = i;
    }
    if (i == n - 1) {
        for (int g = b + 1; g <= N_GRAPHS_C; ++g) start[g] = n;
    }
}

// ---------------------------------------------------------------------------
// Segment mean-pool of relu(emb): no atomics. Block per graph, thread=feature.
// ---------------------------------------------------------------------------
__global__ __launch_bounds__(128) void pool_kernel(
    const float* __restrict__ emb, const int* __restrict__ start,
    float* __restrict__ pooled)
{
    int g = blockIdx.x;
    int f = threadIdx.x;
    int s = start[g], e = start[g + 1];
    float s0 = 0.f, s1 = 0.f, s2 = 0.f, s3 = 0.f;
    int n = s;
    for (; n + 4 <= e; n += 4) {
        s0 += fmaxf(emb[(size_t)(n + 0) * HID_C + f], 0.f);
        s1 += fmaxf(emb[(size_t)(n + 1) * HID_C + f], 0.f);
        s2 += fmaxf(emb[(size_t)(n + 2) * HID_C + f], 0.f);
        s3 += fmaxf(emb[(size_t)(n + 3) * HID_C + f], 0.f);
    }
    for (; n < e; ++n) s0 += fmaxf(emb[(size_t)n * HID_C + f], 0.f);
    float sum = (s0 + s1) + (s2 + s3);
    pooled[(size_t)g * HID_C + f] = sum / fmaxf((float)(e - s), 1.0f);
}

// ---------------------------------------------------------------------------
// Per-graph MLP head + log_softmax. One block (64 threads) per graph.
// ---------------------------------------------------------------------------
__global__ __launch_bounds__(64) void mlp_head_kernel(
    const float* __restrict__ pooled,
    const float* __restrict__ W1,
    const float* __restrict__ b1,
    const float* __restrict__ W2,
    const float* __restrict__ b2,
    float* __restrict__ logits_out)
{
    int g = blockIdx.x;
    int t = threadIdx.x;
    __shared__ float sp[HID_C];
    __shared__ float sh[MLP_HID_C];
    __shared__ float sl[N_CLS_C];

    sp[t] = pooled[(size_t)g * HID_C + t];
    sp[t + 64] = pooled[(size_t)g * HID_C + t + 64];
    __syncthreads();

    if (t < MLP_HID_C) {
        float a = b1[t];
        #pragma unroll 8
        for (int k = 0; k < HID_C; ++k) a += sp[k] * W1[k * MLP_HID_C + t];
        sh[t] = fmaxf(a, 0.0f);
    }
    __syncthreads();

    if (t < N_CLS_C) {
        float a = b2[t];
        #pragma unroll
        for (int k = 0; k < MLP_HID_C; ++k) a += sh[k] * W2[k * N_CLS_C + t];
        sl[t] = a;
    }
    __syncthreads();

    if (t < N_CLS_C) {
        float m = sl[0];
        #pragma unroll
        for (int i = 1; i < N_CLS_C; ++i) m = fmaxf(m, sl[i]);
        float sum = 0.0f;
        #pragma unroll
        for (int i = 0; i < N_CLS_C; ++i) sum += expf(sl[i] - m);
        logits_out[(size_t)g * N_CLS_C + t] = sl[t] - m - logf(sum);
    }
}

extern "C" void kernel_launch(void* const* d_in, const int* in_sizes, int n_in,
                              void* d_out, int out_size, void* d_ws, size_t ws_size,
                              hipStream_t stream) {
    const float* x      = (const float*)d_in[0];
    const int*   ei     = (const int*)d_in[1];
    const int*   batch  = (const int*)d_in[2];
    const float* Wn     = (const float*)d_in[3];
    const float* Ws     = (const float*)d_in[4];
    const float* bias   = (const float*)d_in[5];
    const float* W1     = (const float*)d_in[6];
    const float* b1     = (const float*)d_in[7];
    const float* W2     = (const float*)d_in[8];
    const float* b2     = (const float*)d_in[9];

    float* out = (float*)d_out;

    int n_edges = in_sizes[1] / 2;
    const int* src = ei;
    const int* dst = ei + n_edges;

    // workspace layout (4B units):
    // deg_i[N] | cursor[N] | off[N+1] | bsums[64] | bprefix[64] | start[G+1]
    // | adj[E] | pooled[G*128]
    int* deg_i   = (int*)d_ws;
    int* cursor  = deg_i + N_NODES_C;
    int* off     = cursor + N_NODES_C;
    int* bsums   = off + (N_NODES_C + 1);
    int* bprefix = bsums + 64;
    int* start   = bprefix + 64;
    int* adj     = start + (N_GRAPHS_C + 1);
    float* pooled = (float*)(adj + n_edges);

    // zero only deg_i + cursor (contiguous); everything else fully rewritten
    hipMemsetAsync(d_ws, 0, (size_t)2 * N_NODES_C * sizeof(int), stream);

    int eblk = (n_edges + 255) / 256;
    hist_kernel<<<eblk, 256, 0, stream>>>(dst, deg_i, n_edges);
    scan1_kernel<<<N_SCAN_BLK, 256, 0, stream>>>(deg_i, bsums, N_NODES_C);
    scan2_kernel<<<1, 64, 0, stream>>>(bsums, bprefix, off, N_SCAN_BLK, N_NODES_C);
    scan3_kernel<<<N_SCAN_BLK, 256, 0, stream>>>(deg_i, bprefix, off, N_NODES_C);
    scatter_kernel<<<eblk, 256, 0, stream>>>(src, dst, off, cursor, adj, n_edges);

    int ngroups = (N_NODES_C + 3) / 4;          // 12500
    int gblocks = (ngroups + 7) / 8;            // 1563
    gather_emb_kernel<<<gblocks, 512, 0, stream>>>(x, adj, off, deg_i,
                                                   Wn, Ws, bias, out);

    bounds_kernel<<<(N_NODES_C + 255) / 256, 256, 0, stream>>>(batch, start, N_NODES_C);
    pool_kernel<<<N_GRAPHS_C, 128, 0, stream>>>(out, start, pooled);
    mlp_head_kernel<<<N_GRAPHS_C, 64, 0, stream>>>(pooled, W1, b1, W2, b2,
                                                   out + (size_t)N_NODES_C * HID_C);
}